// Round 9
// baseline (472.681 us; speedup 1.0000x reference)
//
#include <hip/hip_runtime.h>
#include <cstdint>
#include <cstddef>

// ---------- types ----------
typedef __attribute__((ext_vector_type(8))) __bf16 bf16x8;   // MFMA A/B frag (4 VGPRs)
typedef __attribute__((ext_vector_type(4))) float  f32x4;    // MFMA C/D frag

// s_waitcnt simm16 (gfx9/CDNA): [3:0] vmcnt lo, [6:4] expcnt, [11:8] lgkmcnt, [15:14] vmcnt hi
#define WAITCNT_VM(n)   ((n & 0xF) | 0x70 | 0xF00 | (((n) >> 4) << 14))  // wait vmcnt<=n only
#define WAITCNT_LGKM(n) (0xF | 0x70 | ((n) << 8) | (3 << 14))            // wait lgkmcnt<=n only

__device__ __forceinline__ unsigned short f32_to_bf16(float f) {
    union { float f; unsigned int u; } cv;
    cv.f = f;
    unsigned int u = cv.u;
    return (unsigned short)((u + 0x7fffu + ((u >> 16) & 1u)) >> 16);  // RNE
}

__device__ __forceinline__ float bf16_to_f32(unsigned short h) {
    union { unsigned int u; float f; } cv;
    cv.u = ((unsigned int)h) << 16;
    return cv.f;
}

// async global->LDS, 16 bytes per lane. LDS dest is wave-uniform base + lane*16.
__device__ __forceinline__ void async_copy16(const unsigned short* g, unsigned short* lds) {
    __builtin_amdgcn_global_load_lds(
        (const __attribute__((address_space(1))) unsigned int*)g,
        (__attribute__((address_space(3))) unsigned int*)lds,
        16, 0, 0);
}

// ---------- hand-rolled device-scope phase barrier (all 256 blocks co-resident) ----------
// R8 lesson: cg::grid.sync() costs ~34 us each on MI355X; this is ~2-3 us.
__device__ __forceinline__ void gbar(unsigned int* cnt) {
    __syncthreads();
    if (threadIdx.x == 0) {
        __threadfence();   // release all prior global writes device-wide
        __hip_atomic_fetch_add(cnt, 1u, __ATOMIC_ACQ_REL, __HIP_MEMORY_SCOPE_AGENT);
        while (__hip_atomic_load(cnt, __ATOMIC_ACQUIRE, __HIP_MEMORY_SCOPE_AGENT) < 256u) {}
    }
    __syncthreads();
}

// ======================= shared 256x256 geometry macros =======================
#define G256_BAR  __builtin_amdgcn_s_barrier()
#define G256_SB   __builtin_amdgcn_sched_barrier(0)
#define G256_PR1  __builtin_amdgcn_s_setprio(1)
#define G256_PR0  __builtin_amdgcn_s_setprio(0)

// ========== 256x256 / BK=64 / 8-wave core: R3 lookahead + counted lgkm ==========
// Best measured core (scores 46.9 us, R3). Used by ALL GEMM phases.
__device__ __forceinline__ void gemm256_la(
    const unsigned short* __restrict__ A, const unsigned short* __restrict__ B,
    int K, int rowBase, int colBase, int kBeg, int nTiles,
    unsigned short* lds, f32x4 acc[8][4])
{
    const int tid  = threadIdx.x;
    const int lane = tid & 63;
    const int wid  = tid >> 6;
    const int quad = lane >> 4;
    const int r    = lane & 15;
    const int wm   = wid >> 2;
    const int wn   = wid & 3;

    const int row0 = tid >> 3;
    const int chs8 = (((tid & 7) ^ (row0 & 7)) << 3);
    const unsigned short* As = A + (long)(rowBase + row0) * K + chs8 + kBeg;
    const unsigned short* Bs = B + (long)(colBase + row0) * K + chs8 + kBeg;
    const long rstep = (long)K * 64;
    const long hstep = (long)K * 128;
    unsigned short* ldsLane = lds + tid * 8;

    const int aRd = (wm << 13) + (r << 6);
    const int bRd = 16384 + (wn << 12) + (r << 6);
    const int sw0 = ((quad ^ (r & 7)) << 3);
    const int sw1 = (((quad + 4) ^ (r & 7)) << 3);

    auto STG = [&](const unsigned short* src, int ldsOff) {
        async_copy16(src,         ldsLane + ldsOff);
        async_copy16(src + rstep, ldsLane + ldsOff + 4096);
    };

    // prologue: T0 (A+B) -> buf0 (8 loads); B(T1) -> buf1 (4 loads)
    STG(As,         0);
    STG(As + hstep, 8192);
    STG(Bs,         16384);
    STG(Bs + hstep, 24576);
    if (nTiles > 1) {
        STG(Bs + 64,         32768 + 16384);
        STG(Bs + hstep + 64, 32768 + 24576);
    }
    __builtin_amdgcn_s_waitcnt(WAITCNT_VM(4));
    G256_BAR;
    G256_SB;

    bf16x8 aE[4], aO[4], bX[4], bY[4];
#pragma unroll
    for (int i = 0; i < 4; ++i)
        aE[i] = *(const bf16x8*)(lds + aRd + i * 1024 + sw0);
#pragma unroll
    for (int j = 0; j < 4; ++j)
        bX[j] = *(const bf16x8*)(lds + bRd + j * 1024 + sw0);

    for (int T = 0; T < nTiles; ++T) {
        const int cur = (T & 1) << 15;
        const int nxt = cur ^ 32768;

        // P0: read aO=a0h1; MFMA aE x bX -> acc[0..3]; stage A(T+1)h0
#pragma unroll
        for (int i = 0; i < 4; ++i)
            aO[i] = *(const bf16x8*)(lds + cur + aRd + (4 + i) * 1024 + sw0);
        __builtin_amdgcn_s_waitcnt(WAITCNT_LGKM(4));
        G256_SB;
        G256_PR1;
#pragma unroll
        for (int i = 0; i < 4; ++i)
#pragma unroll
            for (int j = 0; j < 4; ++j)
                acc[i][j] = __builtin_amdgcn_mfma_f32_16x16x32_bf16(aE[i], bX[j], acc[i][j], 0, 0, 0);
        G256_PR0;
        G256_SB;
        G256_BAR;
        if (T + 1 < nTiles) STG(As + (T + 1) * 64, nxt);

        // P1: read aE=a1h0, bY=b1; MFMA aO x bX -> acc[4..7]; stage A(T+1)h1
#pragma unroll
        for (int i = 0; i < 4; ++i)
            aE[i] = *(const bf16x8*)(lds + cur + aRd + i * 1024 + sw1);
#pragma unroll
        for (int j = 0; j < 4; ++j)
            bY[j] = *(const bf16x8*)(lds + cur + bRd + j * 1024 + sw1);
        __builtin_amdgcn_s_waitcnt(WAITCNT_LGKM(8));
        G256_SB;
        G256_PR1;
#pragma unroll
        for (int i = 0; i < 4; ++i)
#pragma unroll
            for (int j = 0; j < 4; ++j)
                acc[4 + i][j] = __builtin_amdgcn_mfma_f32_16x16x32_bf16(aO[i], bX[j], acc[4 + i][j], 0, 0, 0);
        G256_PR0;
        G256_SB;
        G256_BAR;
        if (T + 1 < nTiles) STG(As + hstep + (T + 1) * 64, nxt + 8192);

        // P2: read aO=a1h1; MFMA aE x bY -> acc[0..3]; stage B(T+2)h0
#pragma unroll
        for (int i = 0; i < 4; ++i)
            aO[i] = *(const bf16x8*)(lds + cur + aRd + (4 + i) * 1024 + sw1);
        __builtin_amdgcn_s_waitcnt(WAITCNT_LGKM(4));
        G256_SB;
        G256_PR1;
#pragma unroll
        for (int i = 0; i < 4; ++i)
#pragma unroll
            for (int j = 0; j < 4; ++j)
                acc[i][j] = __builtin_amdgcn_mfma_f32_16x16x32_bf16(aE[i], bY[j], acc[i][j], 0, 0, 0);
        G256_PR0;
        G256_SB;
        G256_BAR;
        if (T + 2 < nTiles) STG(Bs + (T + 2) * 64, cur + 16384);

        // P3: boundary; read aE,bX(T+1) from nxt; MFMA aO x bY; stage B(T+2)h1
        if (T + 1 < nTiles) {
            if (T + 2 < nTiles) __builtin_amdgcn_s_waitcnt(WAITCNT_VM(2));
            else                __builtin_amdgcn_s_waitcnt(WAITCNT_VM(0));
            G256_BAR;
            G256_SB;
#pragma unroll
            for (int i = 0; i < 4; ++i)
                aE[i] = *(const bf16x8*)(lds + nxt + aRd + i * 1024 + sw0);
#pragma unroll
            for (int j = 0; j < 4; ++j)
                bX[j] = *(const bf16x8*)(lds + nxt + bRd + j * 1024 + sw0);
            __builtin_amdgcn_s_waitcnt(WAITCNT_LGKM(8));
        } else {
            __builtin_amdgcn_s_waitcnt(WAITCNT_LGKM(0));
        }
        G256_SB;
        G256_PR1;
#pragma unroll
        for (int i = 0; i < 4; ++i)
#pragma unroll
            for (int j = 0; j < 4; ++j)
                acc[4 + i][j] = __builtin_amdgcn_mfma_f32_16x16x32_bf16(aO[i], bY[j], acc[4 + i][j], 0, 0, 0);
        G256_PR0;
        G256_SB;
        if (T + 2 < nTiles) STG(Bs + hstep + (T + 2) * 64, cur + 24576);
    }
}

// ================== PIPELINE KERNEL: whole op, 1 plain launch, sw barriers ==================
// 256 blocks x 512 threads, 128 KB LDS -> exactly 1 block/CU, all co-resident.
// Phases (gbar between each): P0 cast+lsum0 -> P1 proj(192 units) -> P2 scores
// -> P3 out splitK4 -> P4 reduce+norm. Phase code identical to R8's mega (which
// PASSED -> phases + overlay validated); only the sync primitive changed.
__global__ __launch_bounds__(512, 2)
void pipeline(const float* __restrict__ x,  const float* __restrict__ y,
              const float* __restrict__ wq, const float* __restrict__ wk, const float* __restrict__ wv,
              const float* __restrict__ bq, const float* __restrict__ bk, const float* __restrict__ bv,
              unsigned short* __restrict__ xb,  unsigned short* __restrict__ yb,
              unsigned short* __restrict__ wqb, unsigned short* __restrict__ wkb,
              unsigned short* __restrict__ wvb,
              unsigned short* __restrict__ q, unsigned short* __restrict__ k,
              unsigned short* __restrict__ vt, unsigned short* __restrict__ P,
              unsigned short* __restrict__ parts, float* __restrict__ lsum,
              float* __restrict__ O, unsigned int* __restrict__ bar, float scale2)
{
    __shared__ __align__(16) unsigned short lds[2 * 32768];   // 128 KB

    const int tid  = threadIdx.x;
    const int bid  = blockIdx.x;
    const long gtid = (long)bid * 512 + tid;

    // -------- P0: cast all five inputs fp32->bf16 + zero lsum (grid-stride) --------
    {
        float4 z4 = {0.f, 0.f, 0.f, 0.f};
        for (long u = gtid; u < 2884608L; u += 131072L) {   // 1024 lsum-f4 + 2883584 data-f4
            if (u < 1024) { ((float4*)lsum)[u] = z4; continue; }
            long v = u - 1024;
            const float* s; unsigned short* d; long idx;
            if      (v < 1048576L) { s = x;  d = xb;  idx = v; }
            else if (v < 2097152L) { s = y;  d = yb;  idx = v - 1048576L; }
            else if (v < 2359296L) { s = wq; d = wqb; idx = v - 2097152L; }
            else if (v < 2621440L) { s = wk; d = wkb; idx = v - 2359296L; }
            else                   { s = wv; d = wvb; idx = v - 2621440L; }
            float4 vv = ((const float4*)s)[idx];
            ushort4 o;
            o.x = f32_to_bf16(vv.x);
            o.y = f32_to_bf16(vv.y);
            o.z = f32_to_bf16(vv.z);
            o.w = f32_to_bf16(vv.w);
            ((ushort4*)d)[idx] = o;
        }
    }
    gbar(bar + 0);

    const int lane = tid & 63;
    const int wid  = tid >> 6;
    const int quad = lane >> 4;
    const int rr   = lane & 15;

    // -------- P1: projections q,k,vt (192 tile-units; blocks 192..255 idle) --------
    if (bid < 192) {
        const int z  = bid >> 6;
        const int rb = bid & 63;
        const unsigned short *A, *B;
        unsigned short* C;
        const float* bias;
        int Nout, rowBase, colBase;
        bool perRow;
        if (z == 0) {
            A = xb; B = wqb; C = q; bias = bq; Nout = 1024; perRow = false;
            rowBase = (rb >> 2) * 256; colBase = (rb & 3) * 256;
        } else if (z == 1) {
            A = yb; B = wkb; C = k; bias = bk; Nout = 1024; perRow = false;
            rowBase = (rb >> 2) * 256; colBase = (rb & 3) * 256;
        } else {
            A = wvb; B = yb; C = vt; bias = bv; Nout = 4096; perRow = true;
            rowBase = (rb >> 4) * 256; colBase = (rb & 15) * 256;
        }

        f32x4 acc[8][4];
#pragma unroll
        for (int i = 0; i < 8; ++i)
#pragma unroll
            for (int j = 0; j < 4; ++j)
                acc[i][j] = (f32x4){0.f, 0.f, 0.f, 0.f};

        gemm256_la(A, B, 1024, rowBase, colBase, 0, 16, lds, acc);

        const int orow0 = rowBase + (wid >> 2) * 128 + quad * 4;
        const int ocol0 = colBase + (wid & 3) * 64 + rr;
#pragma unroll
        for (int mi = 0; mi < 8; ++mi)
#pragma unroll
            for (int e = 0; e < 4; ++e) {
                const int row = orow0 + mi * 16 + e;
                const float brow = perRow ? bias[row] : 0.f;
#pragma unroll
                for (int nj = 0; nj < 4; ++nj) {
                    const int col = ocol0 + nj * 16;
                    const float bb = perRow ? brow : bias[col];
                    C[(long)row * Nout + col] = f32_to_bf16(acc[mi][nj][e] + bb);
                }
            }
    }
    gbar(bar + 1);

    // -------- P2: scores P = exp2(scale2 * q k^T), lsum row sums --------
    {
        const int swz = (bid & 7) * 32 + (bid >> 3);   // XCD-contiguous, bijective
        const int mt = swz >> 4, nt = swz & 15;
        const int rowBase = mt * 256;
        const int colBase = nt * 256;

        f32x4 acc[8][4];
#pragma unroll
        for (int i = 0; i < 8; ++i)
#pragma unroll
            for (int j = 0; j < 4; ++j)
                acc[i][j] = (f32x4){0.f, 0.f, 0.f, 0.f};

        gemm256_la(q, k, 1024, rowBase, colBase, 0, 16, lds, acc);

        const int orow0 = rowBase + (wid >> 2) * 128 + quad * 4;
        const int ocol0 = colBase + (wid & 3) * 64 + rr;
#pragma unroll
        for (int mi = 0; mi < 8; ++mi)
#pragma unroll
            for (int e = 0; e < 4; ++e) {
                const int row = orow0 + mi * 16 + e;
                float rs = 0.f;
#pragma unroll
                for (int nj = 0; nj < 4; ++nj) {
                    const float p = exp2f(acc[mi][nj][e] * scale2);
                    rs += p;
                    P[(long)row * 4096 + ocol0 + nj * 16] = f32_to_bf16(p);
                }
#pragma unroll
                for (int m = 1; m < 16; m <<= 1) rs += __shfl_xor(rs, m, 64);
                if (rr == 0) atomicAdd(&lsum[row], rs);
            }
    }
    gbar(bar + 2);

    // -------- P3: out = P @ vt^T, split-K x4 -> bf16 partials --------
    {
        const int swz = (bid & 7) * 32 + (bid >> 3);
        const int z  = swz & 3;
        const int nt = (swz >> 2) & 3;
        const int mt = swz >> 4;
        const int rowBase = mt * 256;
        const int colBase = nt * 256;
        const int kBeg = z * 1024;

        f32x4 acc[8][4];
#pragma unroll
        for (int i = 0; i < 8; ++i)
#pragma unroll
            for (int j = 0; j < 4; ++j)
                acc[i][j] = (f32x4){0.f, 0.f, 0.f, 0.f};

        gemm256_la(P, vt, 4096, rowBase, colBase, kBeg, 16, lds, acc);

        unsigned short* part = parts + (size_t)z * (4096 * 1024);
        const int orow0 = rowBase + (wid >> 2) * 128 + quad * 4;
        const int ocol0 = colBase + (wid & 3) * 64 + rr;
#pragma unroll
        for (int mi = 0; mi < 8; ++mi)
#pragma unroll
            for (int e = 0; e < 4; ++e) {
                const int row = orow0 + mi * 16 + e;
#pragma unroll
                for (int nj = 0; nj < 4; ++nj)
                    part[(long)row * 1024 + ocol0 + nj * 16] = f32_to_bf16(acc[mi][nj][e]);
            }
    }
    gbar(bar + 3);

    // -------- P4: O = (p0+p1+p2+p3) / lsum[row] (grid-stride) --------
    {
        const size_t stride = 1048576;   // ushort4 units per part
        for (long i = gtid; i < 1048576L; i += 131072L) {
            const float inv = 1.0f / lsum[i >> 8];
            ushort4 a = ((const ushort4*)parts)[i];
            ushort4 b = ((const ushort4*)parts)[i + stride];
            ushort4 c = ((const ushort4*)parts)[i + 2 * stride];
            ushort4 d = ((const ushort4*)parts)[i + 3 * stride];
            float4 o;
            o.x = (bf16_to_f32(a.x) + bf16_to_f32(b.x) + bf16_to_f32(c.x) + bf16_to_f32(d.x)) * inv;
            o.y = (bf16_to_f32(a.y) + bf16_to_f32(b.y) + bf16_to_f32(c.y) + bf16_to_f32(d.y)) * inv;
            o.z = (bf16_to_f32(a.z) + bf16_to_f32(b.z) + bf16_to_f32(c.z) + bf16_to_f32(d.z)) * inv;
            o.w = (bf16_to_f32(a.w) + bf16_to_f32(b.w) + bf16_to_f32(c.w) + bf16_to_f32(d.w)) * inv;
            ((float4*)O)[i] = o;
        }
    }
}

// ==================== legacy fallback kernels (R3 path, !useParts) ====================
__global__ __launch_bounds__(256) void cast_all(
    const float* __restrict__ x,  const float* __restrict__ y,
    const float* __restrict__ wq, const float* __restrict__ wk, const float* __restrict__ wv,
    unsigned short* __restrict__ xb,  unsigned short* __restrict__ yb,
    unsigned short* __restrict__ wqb, unsigned short* __restrict__ wkb,
    unsigned short* __restrict__ wvb, float* __restrict__ lsum)
{
    int b = blockIdx.x;
    if (b >= 11264) {
        float4 z = {0.f, 0.f, 0.f, 0.f};
#pragma unroll
        for (int t = 0; t < 4; ++t)
            ((float4*)lsum)[threadIdx.x * 4 + t] = z;
        return;
    }
    const float* s; unsigned short* d; int base;
    if      (b < 4096)  { s = x;  d = xb;  base = b; }
    else if (b < 8192)  { s = y;  d = yb;  base = b - 4096; }
    else if (b < 9216)  { s = wq; d = wqb; base = b - 8192; }
    else if (b < 10240) { s = wk; d = wkb; base = b - 9216; }
    else                { s = wv; d = wvb; base = b - 10240; }
    int i = base * 256 + threadIdx.x;
    float4 v = ((const float4*)s)[i];
    ushort4 o;
    o.x = f32_to_bf16(v.x);
    o.y = f32_to_bf16(v.y);
    o.z = f32_to_bf16(v.z);
    o.w = f32_to_bf16(v.w);
    ((ushort4*)d)[i] = o;
}

__global__ __launch_bounds__(512, 2)
void proj256(const unsigned short* __restrict__ xb, const unsigned short* __restrict__ yb,
             const unsigned short* __restrict__ wqb, const unsigned short* __restrict__ wkb,
             const unsigned short* __restrict__ wvb,
             unsigned short* __restrict__ q, unsigned short* __restrict__ k,
             unsigned short* __restrict__ vt,
             const float* __restrict__ bq, const float* __restrict__ bk,
             const float* __restrict__ bv)
{
    __shared__ __align__(16) unsigned short lds[2 * 32768];
    const int bid = blockIdx.x;
    const int z  = bid >> 6;
    const int rb = bid & 63;
    const unsigned short *A, *B;
    unsigned short* C;
    const float* bias;
    int Nout, rowBase, colBase;
    bool perRow;
    if (z == 0) {
        A = xb; B = wqb; C = q; bias = bq; Nout = 1024; perRow = false;
        rowBase = (rb >> 2) * 256; colBase = (rb & 3) * 256;
    } else if (z == 1) {
        A = yb; B = wkb; C = k; bias = bk; Nout = 1024; perRow = false;
        rowBase = (rb >> 2) * 256; colBase = (rb & 3) * 256;
    } else {
        A = wvb; B = yb; C = vt; bias = bv; Nout = 4096; perRow = true;
        rowBase = (rb >> 4) * 256; colBase = (rb & 15) * 256;
    }
    f32x4 acc[8][4];
#pragma unroll
    for (int i = 0; i < 8; ++i)
#pragma unroll
        for (int j = 0; j < 4; ++j)
            acc[i][j] = (f32x4){0.f, 0.f, 0.f, 0.f};
    gemm256_la(A, B, 1024, rowBase, colBase, 0, 16, lds, acc);
    const int lane = threadIdx.x & 63;
    const int wid  = threadIdx.x >> 6;
    const int orow0 = rowBase + (wid >> 2) * 128 + (lane >> 4) * 4;
    const int ocol0 = colBase + (wid & 3) * 64 + (lane & 15);
#pragma unroll
    for (int mi = 0; mi < 8; ++mi)
#pragma unroll
        for (int e = 0; e < 4; ++e) {
            const int row = orow0 + mi * 16 + e;
            const float brow = perRow ? bias[row] : 0.f;
#pragma unroll
            for (int nj = 0; nj < 4; ++nj) {
                const int col = ocol0 + nj * 16;
                const float bb = perRow ? brow : bias[col];
                C[(long)row * Nout + col] = f32_to_bf16(acc[mi][nj][e] + bb);
            }
        }
}

__global__ __launch_bounds__(512, 2)
void scores_gemm256(const unsigned short* __restrict__ q, const unsigned short* __restrict__ k,
                    unsigned short* __restrict__ P, float* __restrict__ lsum, float scale2)
{
    __shared__ __align__(16) unsigned short lds[2 * 32768];
    const int bid = blockIdx.x;
    const int swz = (bid & 7) * 32 + (bid >> 3);
    const int mt = swz >> 4, nt = swz & 15;
    const int rowBase = mt * 256;
    const int colBase = nt * 256;
    f32x4 acc[8][4];
#pragma unroll
    for (int i = 0; i < 8; ++i)
#pragma unroll
        for (int j = 0; j < 4; ++j)
            acc[i][j] = (f32x4){0.f, 0.f, 0.f, 0.f};
    gemm256_la(q, k, 1024, rowBase, colBase, 0, 16, lds, acc);
    const int lane = threadIdx.x & 63;
    const int wid  = threadIdx.x >> 6;
    const int orow0 = rowBase + (wid >> 2) * 128 + (lane >> 4) * 4;
    const int ocol0 = colBase + (wid & 3) * 64 + (lane & 15);
#pragma unroll
    for (int mi = 0; mi < 8; ++mi)
#pragma unroll
        for (int e = 0; e < 4; ++e) {
            const int row = orow0 + mi * 16 + e;
            float rs = 0.f;
#pragma unroll
            for (int nj = 0; nj < 4; ++nj) {
                const float p = exp2f(acc[mi][nj][e] * scale2);
                rs += p;
                P[(long)row * 4096 + ocol0 + nj * 16] = f32_to_bf16(p);
            }
#pragma unroll
            for (int m = 1; m < 16; m <<= 1) rs += __shfl_xor(rs, m, 64);
            if ((lane & 15) == 0) atomicAdd(&lsum[row], rs);
        }
}

__global__ __launch_bounds__(512, 2)
void out_gemm256_atomic(const unsigned short* __restrict__ P, const unsigned short* __restrict__ vt,
                        float* __restrict__ Out)
{
    __shared__ __align__(16) unsigned short lds[2 * 32768];
    const int bid = blockIdx.x;
    const int swz = (bid & 7) * 32 + (bid >> 3);
    const int z  = swz & 3;
    const int nt = (swz >> 2) & 3;
    const int mt = swz >> 4;
    const int rowBase = mt * 256;
    const int colBase = nt * 256;
    f32x4 acc[8][4];
#pragma unroll
    for (int i = 0; i < 8; ++i)
#pragma unroll
        for (int j = 0; j < 4; ++j)
            acc[i][j] = (f32x4){0.f, 0.f, 0.f, 0.f};
    gemm256_la(P, vt, 4096, rowBase, colBase, z * 1024, 16, lds, acc);
    const int lane = threadIdx.x & 63;
    const int wid  = threadIdx.x >> 6;
    const int orow0 = rowBase + (wid >> 2) * 128 + (lane >> 4) * 4;
    const int ocol0 = colBase + (wid & 3) * 64 + (lane & 15);
#pragma unroll
    for (int mi = 0; mi < 8; ++mi)
#pragma unroll
        for (int e = 0; e < 4; ++e) {
            const int row = orow0 + mi * 16 + e;
#pragma unroll
            for (int nj = 0; nj < 4; ++nj)
                atomicAdd(&Out[(long)row * 1024 + ocol0 + nj * 16], acc[mi][nj][e]);
        }
}

__global__ __launch_bounds__(256) void norm_rows(float* __restrict__ O, const float* __restrict__ lsum) {
    int i = blockIdx.x * 256 + threadIdx.x;
    const float inv = 1.0f / lsum[i >> 8];
    float4 v = ((const float4*)O)[i];
    v.x *= inv; v.y *= inv; v.z *= inv; v.w *= inv;
    ((float4*)O)[i] = v;
}

extern "C" void kernel_launch(void* const* d_in, const int* in_sizes, int n_in,
                              void* d_out, int out_size, void* d_ws, size_t ws_size,
                              hipStream_t stream) {
    const float* x  = (const float*)d_in[0];
    const float* y  = (const float*)d_in[1];
    const float* Wq = (const float*)d_in[2];
    const float* bq = (const float*)d_in[3];
    const float* Wk = (const float*)d_in[4];
    const float* bk = (const float*)d_in[5];
    const float* Wv = (const float*)d_in[6];
    const float* bv = (const float*)d_in[7];

    constexpr int Nx = 4096, Ny = 4096, H = 1024, Dv = 1024, Kin = 1024;

    char* ws = (char*)d_ws;
    size_t off = 0;
    auto carve = [&](size_t bytes) {
        char* p = ws + off;
        off += (bytes + 255) & ~(size_t)255;
        return p;
    };

    unsigned int*   bar   = (unsigned int*)carve(256);                    // 4 barrier counters
    unsigned short* q_bf  = (unsigned short*)carve((size_t)Nx * H * 2);   // 8 MB
    unsigned short* k_bf  = (unsigned short*)carve((size_t)Ny * H * 2);   // 8 MB
    unsigned short* vt_bf = (unsigned short*)carve((size_t)Dv * Ny * 2);  // 8 MB
    float*          lsum  = (float*)carve((size_t)Nx * sizeof(float));    // 16 KB

    // overlay: phase 0/1 = bf16 casts (22 MB), phase 2+ = P (32 MB)
    char* overlay = ws + off;
    unsigned short* x_bf  = (unsigned short*)overlay;
    unsigned short* y_bf  = x_bf  + (size_t)Nx * Kin;
    unsigned short* Wq_bf = y_bf  + (size_t)Ny * Kin;
    unsigned short* Wk_bf = Wq_bf + (size_t)H  * Kin;
    unsigned short* Wv_bf = Wk_bf + (size_t)H  * Kin;
    unsigned short* P_bf  = (unsigned short*)overlay;  // [Nx, Ny] bf16, phase 2

    const size_t overlay_bytes = (size_t)Nx * Ny * 2;                 // 32 MB
    const size_t partsBytes = (size_t)Nx * Dv * 2;                    // 8 MB each
    unsigned short* parts = (unsigned short*)(overlay + overlay_bytes);
    const size_t need_parts = (size_t)((overlay + overlay_bytes + 4 * partsBytes) - ws);
    const bool useParts = ws_size >= need_parts;

    float scale2 = 1.4426950408889634f / 32.0f;  // log2(e)/sqrt(H)
    float* outF = (float*)d_out;

    if (useParts) {
        // ---- zero barrier counters, then one plain (graph-capturable) launch ----
        (void)hipMemsetAsync(bar, 0, 64, stream);
        pipeline<<<256, 512, 0, stream>>>(
            x, y, Wq, Wk, Wv, bq, bk, bv,
            x_bf, y_bf, Wq_bf, Wk_bf, Wv_bf,
            q_bf, k_bf, vt_bf, P_bf, parts, lsum, outF, bar, scale2);
    } else {
        // ---- legacy multi-kernel path (R3 config) ----
        (void)hipMemsetAsync(d_out, 0, (size_t)Nx * Dv * sizeof(float), stream);
        cast_all<<<11265, 256, 0, stream>>>(x, y, Wq, Wk, Wv, x_bf, y_bf, Wq_bf, Wk_bf, Wv_bf, lsum);
        proj256<<<192, 512, 0, stream>>>(x_bf, y_bf, Wq_bf, Wk_bf, Wv_bf,
                                         q_bf, k_bf, vt_bf, bq, bk, bv);
        scores_gemm256<<<256, 512, 0, stream>>>(q_bf, k_bf, P_bf, lsum, scale2);
        out_gemm256_atomic<<<256, 512, 0, stream>>>(P_bf, vt_bf, outF);
        norm_rows<<<Nx * Dv / 4 / 256, 256, 0, stream>>>(outF, lsum);
    }
}

// Round 10
// 259.544 us; speedup vs baseline: 1.8212x; 1.8212x over previous
//
#include <hip/hip_runtime.h>
#include <cstdint>
#include <cstddef>

// ---------- types ----------
typedef __attribute__((ext_vector_type(8))) __bf16 bf16x8;   // MFMA A/B frag (4 VGPRs)
typedef __attribute__((ext_vector_type(4))) float  f32x4;    // MFMA C/D frag

// s_waitcnt simm16 (gfx9/CDNA): [3:0] vmcnt lo, [6:4] expcnt, [11:8] lgkmcnt, [15:14] vmcnt hi
#define WAITCNT_VM(n)   ((n & 0xF) | 0x70 | 0xF00 | (((n) >> 4) << 14))  // wait vmcnt<=n only
#define WAITCNT_LGKM(n) (0xF | 0x70 | ((n) << 8) | (3 << 14))            // wait lgkmcnt<=n only

__device__ __forceinline__ unsigned short f32_to_bf16(float f) {
    union { float f; unsigned int u; } cv;
    cv.f = f;
    unsigned int u = cv.u;
    return (unsigned short)((u + 0x7fffu + ((u >> 16) & 1u)) >> 16);  // RNE
}

__device__ __forceinline__ float bf16_to_f32(unsigned short h) {
    union { unsigned int u; float f; } cv;
    cv.u = ((unsigned int)h) << 16;
    return cv.f;
}

// async global->LDS, 16 bytes per lane. LDS dest is wave-uniform base + lane*16.
__device__ __forceinline__ void async_copy16(const unsigned short* g, unsigned short* lds) {
    __builtin_amdgcn_global_load_lds(
        (const __attribute__((address_space(1))) unsigned int*)g,
        (__attribute__((address_space(3))) unsigned int*)lds,
        16, 0, 0);
}

// ---------- fused fp32 -> bf16 cast for all five inputs + lsum zeroing ----------
__global__ __launch_bounds__(256) void cast_all(
    const float* __restrict__ x,  const float* __restrict__ y,
    const float* __restrict__ wq, const float* __restrict__ wk, const float* __restrict__ wv,
    unsigned short* __restrict__ xb,  unsigned short* __restrict__ yb,
    unsigned short* __restrict__ wqb, unsigned short* __restrict__ wkb,
    unsigned short* __restrict__ wvb, float* __restrict__ lsum)
{
    int b = blockIdx.x;
    if (b >= 11264) {   // last block: zero lsum[4096]
        float4 z = {0.f, 0.f, 0.f, 0.f};
#pragma unroll
        for (int t = 0; t < 4; ++t)
            ((float4*)lsum)[threadIdx.x * 4 + t] = z;
        return;
    }
    const float* s; unsigned short* d; int base;
    if      (b < 4096)  { s = x;  d = xb;  base = b; }
    else if (b < 8192)  { s = y;  d = yb;  base = b - 4096; }
    else if (b < 9216)  { s = wq; d = wqb; base = b - 8192; }
    else if (b < 10240) { s = wk; d = wkb; base = b - 9216; }
    else                { s = wv; d = wvb; base = b - 10240; }
    int i = base * 256 + threadIdx.x;
    float4 v = ((const float4*)s)[i];
    ushort4 o;
    o.x = f32_to_bf16(v.x);
    o.y = f32_to_bf16(v.y);
    o.z = f32_to_bf16(v.z);
    o.w = f32_to_bf16(v.w);
    ((ushort4*)d)[i] = o;
}

// ---------- 1-deep prefetch GEMM core, BK=32 (proven; used by proj only) ----------
__device__ __forceinline__ void gemm_core_pf(
    const unsigned short* __restrict__ A, const unsigned short* __restrict__ B,
    int K, int rowBase, int colBase, int kBeg, int kEnd,
    unsigned short* ldsA, unsigned short* ldsB, f32x4 acc[4][4])
{
    const int tid  = threadIdx.x;
    const int lane = tid & 63;
    const int wave = tid >> 6;
    const int quad = lane >> 4;
    const int r    = lane & 15;
    const int wm   = wave >> 1;
    const int wn   = wave & 1;

    const int c1 = tid + 256;
    const long aOff0 = (long)(rowBase + (tid >> 2)) * K + (tid & 3) * 8;
    const long aOff1 = (long)(rowBase + (c1  >> 2)) * K + (c1  & 3) * 8;
    const long bOff0 = (long)(colBase + (tid >> 2)) * K + (tid & 3) * 8;
    const long bOff1 = (long)(colBase + (c1  >> 2)) * K + (c1  & 3) * 8;
    unsigned short* ldsA0 = ldsA + tid * 8;
    unsigned short* ldsA1 = ldsA + c1 * 8;
    unsigned short* ldsB0 = ldsB + tid * 8;
    unsigned short* ldsB1 = ldsB + c1 * 8;

    const int aReadOff = (wm * 64 + r) * 32 + quad * 8;
    const int bReadOff = (wn * 64 + r) * 32 + quad * 8;

    const int nSteps = (kEnd - kBeg) >> 5;

    async_copy16(A + aOff0 + kBeg, ldsA0);
    async_copy16(A + aOff1 + kBeg, ldsA1);
    async_copy16(B + bOff0 + kBeg, ldsB0);
    async_copy16(B + bOff1 + kBeg, ldsB1);

    for (int s = 0; s < nSteps; ++s) {
        const int cur = (s & 1) << 12;          // 0 or 4096 elems
        const int nxt = cur ^ 4096;
        __builtin_amdgcn_s_waitcnt(0);          // tile s arrived
        __syncthreads();                        // visible to all; buf[nxt] free
        if (s + 1 < nSteps) {
            const int kn = kBeg + ((s + 1) << 5);
            async_copy16(A + aOff0 + kn, ldsA0 + nxt);
            async_copy16(A + aOff1 + kn, ldsA1 + nxt);
            async_copy16(B + bOff0 + kn, ldsB0 + nxt);
            async_copy16(B + bOff1 + kn, ldsB1 + nxt);
        }
        bf16x8 af[4], bfr[4];
#pragma unroll
        for (int i = 0; i < 4; ++i)
            af[i] = *(const bf16x8*)(ldsA + cur + aReadOff + i * 16 * 32);
#pragma unroll
        for (int j = 0; j < 4; ++j)
            bfr[j] = *(const bf16x8*)(ldsB + cur + bReadOff + j * 16 * 32);
#pragma unroll
        for (int i = 0; i < 4; ++i)
#pragma unroll
            for (int j = 0; j < 4; ++j)
                acc[i][j] = __builtin_amdgcn_mfma_f32_16x16x32_bf16(af[i], bfr[j], acc[i][j], 0, 0, 0);
    }
}

// ---------- batched projections: 768 blocks (3 problems x 256), K=1024 ----------
__global__ __launch_bounds__(256, 2)
void proj_batched(const unsigned short* __restrict__ xb, const unsigned short* __restrict__ yb,
                  const unsigned short* __restrict__ wqb, const unsigned short* __restrict__ wkb,
                  const unsigned short* __restrict__ wvb,
                  unsigned short* __restrict__ q, unsigned short* __restrict__ k,
                  unsigned short* __restrict__ vt,
                  const float* __restrict__ bq, const float* __restrict__ bk,
                  const float* __restrict__ bv)
{
    __shared__ __align__(16) unsigned short ldsA[2 * 128 * 32];
    __shared__ __align__(16) unsigned short ldsB[2 * 128 * 32];

    const int b = blockIdx.x;
    const int z = b >> 8;
    const int rb = b & 255;

    const unsigned short *A, *B;
    unsigned short* C;
    const float* bias;
    int N, rowBase, colBase;
    bool biasPerRow;
    if (z == 0) {
        A = xb; B = wqb; C = q; bias = bq; N = 1024; biasPerRow = false;
        colBase = (rb >> 5) * 128; rowBase = (rb & 31) * 128;
    } else if (z == 1) {
        A = yb; B = wkb; C = k; bias = bk; N = 1024; biasPerRow = false;
        colBase = (rb >> 5) * 128; rowBase = (rb & 31) * 128;
    } else {
        A = wvb; B = yb; C = vt; bias = bv; N = 4096; biasPerRow = true;
        colBase = (rb >> 3) * 128; rowBase = (rb & 7) * 128;
    }

    f32x4 acc[4][4];
#pragma unroll
    for (int i = 0; i < 4; ++i)
#pragma unroll
        for (int j = 0; j < 4; ++j)
            acc[i][j] = (f32x4){0.f, 0.f, 0.f, 0.f};

    gemm_core_pf(A, B, 1024, rowBase, colBase, 0, 1024, ldsA, ldsB, acc);

    const int lane = threadIdx.x & 63;
    const int wave = threadIdx.x >> 6;
    const int quad = lane >> 4;
    const int r    = lane & 15;
    const int orow0 = rowBase + (wave >> 1) * 64 + quad * 4;
    const int ocol0 = colBase + (wave & 1) * 64 + r;

#pragma unroll
    for (int i = 0; i < 4; ++i)
#pragma unroll
        for (int e = 0; e < 4; ++e) {
            const int row = orow0 + i * 16 + e;
            const float brow = biasPerRow ? bias[row] : 0.f;
#pragma unroll
            for (int j = 0; j < 4; ++j) {
                const int col = ocol0 + j * 16;
                const float bb = biasPerRow ? brow : bias[col];
                C[(long)row * N + col] = f32_to_bf16(acc[i][j][e] + bb);
            }
        }
}

// ======================= shared 256x256 geometry macros =======================
#define G256_BAR  __builtin_amdgcn_s_barrier()
#define G256_SB   __builtin_amdgcn_sched_barrier(0)
#define G256_PR1  __builtin_amdgcn_s_setprio(1)
#define G256_PR0  __builtin_amdgcn_s_setprio(0)

// ========== 256x256 / BK=64 / 8-wave core: R3 lookahead + counted lgkm ==========
// Best measured core (scores 46.9 us, R3). Used by scores and out.
__device__ __forceinline__ void gemm256_la(
    const unsigned short* __restrict__ A, const unsigned short* __restrict__ B,
    int K, int rowBase, int colBase, int kBeg, int nTiles,
    unsigned short* lds, f32x4 acc[8][4])
{
    const int tid  = threadIdx.x;
    const int lane = tid & 63;
    const int wid  = tid >> 6;
    const int quad = lane >> 4;
    const int r    = lane & 15;
    const int wm   = wid >> 2;
    const int wn   = wid & 3;

    const int row0 = tid >> 3;
    const int chs8 = (((tid & 7) ^ (row0 & 7)) << 3);
    const unsigned short* As = A + (long)(rowBase + row0) * K + chs8 + kBeg;
    const unsigned short* Bs = B + (long)(colBase + row0) * K + chs8 + kBeg;
    const long rstep = (long)K * 64;
    const long hstep = (long)K * 128;
    unsigned short* ldsLane = lds + tid * 8;

    const int aRd = (wm << 13) + (r << 6);
    const int bRd = 16384 + (wn << 12) + (r << 6);
    const int sw0 = ((quad ^ (r & 7)) << 3);
    const int sw1 = (((quad + 4) ^ (r & 7)) << 3);

    auto STG = [&](const unsigned short* src, int ldsOff) {
        async_copy16(src,         ldsLane + ldsOff);
        async_copy16(src + rstep, ldsLane + ldsOff + 4096);
    };

    // prologue: T0 (A+B) -> buf0 (8 loads); B(T1) -> buf1 (4 loads)
    STG(As,         0);
    STG(As + hstep, 8192);
    STG(Bs,         16384);
    STG(Bs + hstep, 24576);
    if (nTiles > 1) {
        STG(Bs + 64,         32768 + 16384);
        STG(Bs + hstep + 64, 32768 + 24576);
    }
    __builtin_amdgcn_s_waitcnt(WAITCNT_VM(4));
    G256_BAR;
    G256_SB;

    bf16x8 aE[4], aO[4], bX[4], bY[4];
#pragma unroll
    for (int i = 0; i < 4; ++i)
        aE[i] = *(const bf16x8*)(lds + aRd + i * 1024 + sw0);
#pragma unroll
    for (int j = 0; j < 4; ++j)
        bX[j] = *(const bf16x8*)(lds + bRd + j * 1024 + sw0);

    for (int T = 0; T < nTiles; ++T) {
        const int cur = (T & 1) << 15;
        const int nxt = cur ^ 32768;

        // P0: read aO=a0h1; MFMA aE x bX -> acc[0..3]; stage A(T+1)h0
#pragma unroll
        for (int i = 0; i < 4; ++i)
            aO[i] = *(const bf16x8*)(lds + cur + aRd + (4 + i) * 1024 + sw0);
        __builtin_amdgcn_s_waitcnt(WAITCNT_LGKM(4));
        G256_SB;
        G256_PR1;
#pragma unroll
        for (int i = 0; i < 4; ++i)
#pragma unroll
            for (int j = 0; j < 4; ++j)
                acc[i][j] = __builtin_amdgcn_mfma_f32_16x16x32_bf16(aE[i], bX[j], acc[i][j], 0, 0, 0);
        G256_PR0;
        G256_SB;
        G256_BAR;
        if (T + 1 < nTiles) STG(As + (T + 1) * 64, nxt);

        // P1: read aE=a1h0, bY=b1; MFMA aO x bX -> acc[4..7]; stage A(T+1)h1
#pragma unroll
        for (int i = 0; i < 4; ++i)
            aE[i] = *(const bf16x8*)(lds + cur + aRd + i * 1024 + sw1);
#pragma unroll
        for (int j = 0; j < 4; ++j)
            bY[j] = *(const bf16x8*)(lds + cur + bRd + j * 1024 + sw1);
        __builtin_amdgcn_s_waitcnt(WAITCNT_LGKM(8));
        G256_SB;
        G256_PR1;
#pragma unroll
        for (int i = 0; i < 4; ++i)
#pragma unroll
            for (int j = 0; j < 4; ++j)
                acc[4 + i][j] = __builtin_amdgcn_mfma_f32_16x16x32_bf16(aO[i], bX[j], acc[4 + i][j], 0, 0, 0);
        G256_PR0;
        G256_SB;
        G256_BAR;
        if (T + 1 < nTiles) STG(As + hstep + (T + 1) * 64, nxt + 8192);

        // P2: read aO=a1h1; MFMA aE x bY -> acc[0..3]; stage B(T+2)h0
#pragma unroll
        for (int i = 0; i < 4; ++i)
            aO[i] = *(const bf16x8*)(lds + cur + aRd + (4 + i) * 1024 + sw1);
        __builtin_amdgcn_s_waitcnt(WAITCNT_LGKM(4));
        G256_SB;
        G256_PR1;
#pragma unroll
        for (int i = 0; i < 4; ++i)
#pragma unroll
            for (int j = 0; j < 4; ++j)
                acc[i][j] = __builtin_amdgcn_mfma_f32_16x16x32_bf16(aE[i], bY[j], acc[i][j], 0, 0, 0);
        G256_PR0;
        G256_SB;
        G256_BAR;
        if (T + 2 < nTiles) STG(Bs + (T + 2) * 64, cur + 16384);

        // P3: boundary; read aE,bX(T+1) from nxt; MFMA aO x bY; stage B(T+2)h1
        if (T + 1 < nTiles) {
            if (T + 2 < nTiles) __builtin_amdgcn_s_waitcnt(WAITCNT_VM(2));
            else                __builtin_amdgcn_s_waitcnt(WAITCNT_VM(0));
            G256_BAR;
            G256_SB;
#pragma unroll
            for (int i = 0; i < 4; ++i)
                aE[i] = *(const bf16x8*)(lds + nxt + aRd + i * 1024 + sw0);
#pragma unroll
            for (int j = 0; j < 4; ++j)
                bX[j] = *(const bf16x8*)(lds + nxt + bRd + j * 1024 + sw0);
            __builtin_amdgcn_s_waitcnt(WAITCNT_LGKM(8));
        } else {
            __builtin_amdgcn_s_waitcnt(WAITCNT_LGKM(0));
        }
        G256_SB;
        G256_PR1;
#pragma unroll
        for (int i = 0; i < 4; ++i)
#pragma unroll
            for (int j = 0; j < 4; ++j)
                acc[4 + i][j] = __builtin_amdgcn_mfma_f32_16x16x32_bf16(aO[i], bY[j], acc[4 + i][j], 0, 0, 0);
        G256_PR0;
        G256_SB;
        if (T + 2 < nTiles) STG(Bs + hstep + (T + 2) * 64, cur + 24576);
    }
}

// ---------- scores (256^2): P = exp2(scale2 * (q @ k^T)) bf16, lsum[row] += rowsum ----------
__global__ __launch_bounds__(512, 2)
void scores_gemm256(const unsigned short* __restrict__ q, const unsigned short* __restrict__ k,
                    unsigned short* __restrict__ P, float* __restrict__ lsum, float scale2)
{
    __shared__ __align__(16) unsigned short lds[2 * 32768];   // 128 KB

    const int bid = blockIdx.x;                    // 256 blocks
    const int swz = (bid & 7) * 32 + (bid >> 3);   // XCD-contiguous, bijective
    const int mt = swz >> 4, nt = swz & 15;
    const int rowBase = mt * 256;
    const int colBase = nt * 256;

    f32x4 acc[8][4];
#pragma unroll
    for (int i = 0; i < 8; ++i)
#pragma unroll
        for (int j = 0; j < 4; ++j)
            acc[i][j] = (f32x4){0.f, 0.f, 0.f, 0.f};

    gemm256_la(q, k, 1024, rowBase, colBase, 0, 16, lds, acc);

    const int lane = threadIdx.x & 63;
    const int wid  = threadIdx.x >> 6;
    const int quad = lane >> 4;
    const int r    = lane & 15;
    const int orow0 = rowBase + (wid >> 2) * 128 + quad * 4;
    const int ocol0 = colBase + (wid & 3) * 64 + r;

#pragma unroll
    for (int mi = 0; mi < 8; ++mi)
#pragma unroll
        for (int e = 0; e < 4; ++e) {
            const int row = orow0 + mi * 16 + e;
            float rs = 0.f;
#pragma unroll
            for (int nj = 0; nj < 4; ++nj) {
                const float p = exp2f(acc[mi][nj][e] * scale2);
                rs += p;
                P[(long)row * 4096 + ocol0 + nj * 16] = f32_to_bf16(p);
            }
#pragma unroll
            for (int m = 1; m < 16; m <<= 1) rs += __shfl_xor(rs, m, 64);
            if (r == 0) atomicAdd(&lsum[row], rs);
        }
}

// ---------- output GEMM (256^2), split-K x4, SEMAPHORE-FUSED reduce+norm ----------
// Each of the 4 z-blocks per (mt,nt) tile stores its bf16 partial, fences, bumps the
// per-tile counter (device-scope ACQ_REL — the R9-validated protocol). The 4th arrival
// re-reads all 4 partials, divides by lsum, writes O. No grid-wide barrier; per-tile
// point-to-point ordering only. Early tiles reduce while late tiles still GEMM.
__global__ __launch_bounds__(512, 2)
void out_gemm256_fused(const unsigned short* __restrict__ P, const unsigned short* __restrict__ vt,
                       unsigned short* __restrict__ parts, const float* __restrict__ lsum,
                       float* __restrict__ O, unsigned int* __restrict__ cnt)
{
    __shared__ __align__(16) unsigned short lds[2 * 32768];   // 128 KB
    __shared__ unsigned int sOld;

    const int bid = blockIdx.x;
    const int swz = (bid & 7) * 32 + (bid >> 3);
    const int z  = swz & 3;
    const int nt = (swz >> 2) & 3;
    const int mt = swz >> 4;
    const int rowBase = mt * 256;
    const int colBase = nt * 256;
    const int kBeg = z * 1024;

    f32x4 acc[8][4];
#pragma unroll
    for (int i = 0; i < 8; ++i)
#pragma unroll
        for (int j = 0; j < 4; ++j)
            acc[i][j] = (f32x4){0.f, 0.f, 0.f, 0.f};

    gemm256_la(P, vt, 4096, rowBase, colBase, kBeg, 16, lds, acc);

    const int lane = threadIdx.x & 63;
    const int wid  = threadIdx.x >> 6;
    const int quad = lane >> 4;
    const int r    = lane & 15;
    const int orow0 = rowBase + (wid >> 2) * 128 + quad * 4;
    const int ocol0 = colBase + (wid & 3) * 64 + r;

    unsigned short* part = parts + (size_t)z * (4096 * 1024);
#pragma unroll
    for (int mi = 0; mi < 8; ++mi)
#pragma unroll
        for (int e = 0; e < 4; ++e) {
            const int row = orow0 + mi * 16 + e;
#pragma unroll
            for (int nj = 0; nj < 4; ++nj)
                part[(long)row * 1024 + ocol0 + nj * 16] = f32_to_bf16(acc[mi][nj][e]);
        }

    // ---- per-tile semaphore: last of the 4 z-blocks reduces + normalizes ----
    __syncthreads();                       // all partial stores issued block-wide
    if (threadIdx.x == 0) {
        __threadfence();                   // release: partials visible device-scope
        sOld = __hip_atomic_fetch_add(&cnt[mt * 4 + nt], 1u,
                                      __ATOMIC_ACQ_REL, __HIP_MEMORY_SCOPE_AGENT);
    }
    __syncthreads();
    if (sOld == 3u) {
        __threadfence();                   // acquire: see other blocks' partials
        const size_t stride = 1048576;     // ushort4 units per part (4096*1024/4)
        for (int idx = threadIdx.x; idx < 256 * 64; idx += 512) {
            const int rrow = idx >> 6;     // 0..255
            const int c4   = idx & 63;     // 0..63 ushort4 cols
            const long i = (long)(rowBase + rrow) * 256 + (colBase >> 2) + c4;
            const float inv = 1.0f / lsum[rowBase + rrow];
            ushort4 a = ((const ushort4*)parts)[i];
            ushort4 b = ((const ushort4*)parts)[i + stride];
            ushort4 c = ((const ushort4*)parts)[i + 2 * stride];
            ushort4 d = ((const ushort4*)parts)[i + 3 * stride];
            float4 o;
            o.x = (bf16_to_f32(a.x) + bf16_to_f32(b.x) + bf16_to_f32(c.x) + bf16_to_f32(d.x)) * inv;
            o.y = (bf16_to_f32(a.y) + bf16_to_f32(b.y) + bf16_to_f32(c.y) + bf16_to_f32(d.y)) * inv;
            o.z = (bf16_to_f32(a.z) + bf16_to_f32(b.z) + bf16_to_f32(c.z) + bf16_to_f32(d.z)) * inv;
            o.w = (bf16_to_f32(a.w) + bf16_to_f32(b.w) + bf16_to_f32(c.w) + bf16_to_f32(d.w)) * inv;
            ((float4*)O)[i] = o;
        }
    }
}

// ---------- fallback: atomic out + norm (no parts workspace) ----------
__global__ __launch_bounds__(512, 2)
void out_gemm256_atomic(const unsigned short* __restrict__ P, const unsigned short* __restrict__ vt,
                        float* __restrict__ Out)
{
    __shared__ __align__(16) unsigned short lds[2 * 32768];
    const int bid = blockIdx.x;
    const int swz = (bid & 7) * 32 + (bid >> 3);
    const int z  = swz & 3;
    const int nt = (swz >> 2) & 3;
    const int mt = swz >> 4;
    const int rowBase = mt * 256;
    const int colBase = nt * 256;
    f32x4 acc[8][4];
#pragma unroll
    for (int i = 0; i < 8; ++i)
#pragma unroll
        for (int j = 0; j < 4; ++j)
            acc[i][j] = (f32x4){0.f, 0.f, 0.f, 0.f};
    gemm256_la(P, vt, 4096, rowBase, colBase, z * 1024, 16, lds, acc);
    const int lane = threadIdx.x & 63;
    const int wid  = threadIdx.x >> 6;
    const int orow0 = rowBase + (wid >> 2) * 128 + (lane >> 4) * 4;
    const int ocol0 = colBase + (wid & 3) * 64 + (lane & 15);
#pragma unroll
    for (int mi = 0; mi < 8; ++mi)
#pragma unroll
        for (int e = 0; e < 4; ++e) {
            const int row = orow0 + mi * 16 + e;
#pragma unroll
            for (int nj = 0; nj < 4; ++nj)
                atomicAdd(&Out[(long)row * 1024 + ocol0 + nj * 16], acc[mi][nj][e]);
        }
}

__global__ __launch_bounds__(256) void norm_rows(float* __restrict__ O, const float* __restrict__ lsum) {
    int i = blockIdx.x * 256 + threadIdx.x;
    const float inv = 1.0f / lsum[i >> 8];
    float4 v = ((const float4*)O)[i];
    v.x *= inv; v.y *= inv; v.z *= inv; v.w *= inv;
    ((float4*)O)[i] = v;
}

extern "C" void kernel_launch(void* const* d_in, const int* in_sizes, int n_in,
                              void* d_out, int out_size, void* d_ws, size_t ws_size,
                              hipStream_t stream) {
    const float* x  = (const float*)d_in[0];
    const float* y  = (const float*)d_in[1];
    const float* Wq = (const float*)d_in[2];
    const float* bq = (const float*)d_in[3];
    const float* Wk = (const float*)d_in[4];
    const float* bk = (const float*)d_in[5];
    const float* Wv = (const float*)d_in[6];
    const float* bv = (const float*)d_in[7];

    constexpr int Nx = 4096, Ny = 4096, H = 1024, Dv = 1024, Kin = 1024;

    char* ws = (char*)d_ws;
    size_t off = 0;
    auto carve = [&](size_t bytes) {
        char* p = ws + off;
        off += (bytes + 255) & ~(size_t)255;
        return p;
    };

    unsigned int*   cnt   = (unsigned int*)carve(256);                    // 64 tile counters
    unsigned short* q_bf  = (unsigned short*)carve((size_t)Nx * H * 2);   // 8 MB
    unsigned short* k_bf  = (unsigned short*)carve((size_t)Ny * H * 2);   // 8 MB
    unsigned short* vt_bf = (unsigned short*)carve((size_t)Dv * Ny * 2);  // 8 MB
    float*          lsum  = (float*)carve((size_t)Nx * sizeof(float));    // 16 KB

    // overlay: phase 0/1 = bf16 casts (22 MB), phase 2+ = P (32 MB)
    char* overlay = ws + off;
    unsigned short* x_bf  = (unsigned short*)overlay;
    unsigned short* y_bf  = x_bf  + (size_t)Nx * Kin;
    unsigned short* Wq_bf = y_bf  + (size_t)Ny * Kin;
    unsigned short* Wk_bf = Wq_bf + (size_t)H  * Kin;
    unsigned short* Wv_bf = Wk_bf + (size_t)H  * Kin;
    unsigned short* P_bf  = (unsigned short*)overlay;  // [Nx, Ny] bf16, phase 2

    const size_t overlay_bytes = (size_t)Nx * Ny * 2;                 // 32 MB
    const size_t partsBytes = (size_t)Nx * Dv * 2;                    // 8 MB each
    unsigned short* parts = (unsigned short*)(overlay + overlay_bytes);
    const size_t need_parts = (size_t)((overlay + overlay_bytes + 4 * partsBytes) - ws);
    const bool useParts = ws_size >= need_parts;

    const float scale2 = 1.4426950408889634f / 32.0f;  // log2(e)/sqrt(H)
    float* outF = (float*)d_out;

    if (useParts) {
        // R3 config + semaphore-fused out+reduce (4 dispatches + tiny memset)
        (void)hipMemsetAsync(cnt, 0, 256, stream);
        cast_all<<<11265, 256, 0, stream>>>(x, y, Wq, Wk, Wv, x_bf, y_bf, Wq_bf, Wk_bf, Wv_bf, lsum);
        proj_batched<<<768, 256, 0, stream>>>(x_bf, y_bf, Wq_bf, Wk_bf, Wv_bf,
                                              q_bf, k_bf, vt_bf, bq, bk, bv);
        scores_gemm256<<<256, 512, 0, stream>>>(q_bf, k_bf, P_bf, lsum, scale2);
        out_gemm256_fused<<<256, 512, 0, stream>>>(P_bf, vt_bf, parts, lsum, outF, cnt);
    } else {
        // legacy fallback: atomic out + norm
        (void)hipMemsetAsync(d_out, 0, (size_t)Nx * Dv * sizeof(float), stream);
        cast_all<<<11265, 256, 0, stream>>>(x, y, Wq, Wk, Wv, x_bf, y_bf, Wq_bf, Wk_bf, Wv_bf, lsum);
        proj_batched<<<768, 256, 0, stream>>>(x_bf, y_bf, Wq_bf, Wk_bf, Wv_bf,
                                              q_bf, k_bf, vt_bf, bq, bk, bv);
        scores_gemm256<<<256, 512, 0, stream>>>(q_bf, k_bf, P_bf, lsum, scale2);
        out_gemm256_atomic<<<256, 512, 0, stream>>>(P_bf, vt_bf, outF);
        norm_rows<<<Nx * Dv / 4 / 256, 256, 0, stream>>>(outF, lsum);
    }
}

// Round 11
// 225.725 us; speedup vs baseline: 2.0941x; 1.1498x over previous
//
#include <hip/hip_runtime.h>
#include <cstdint>
#include <cstddef>

// ---------- types ----------
typedef __attribute__((ext_vector_type(8))) __bf16 bf16x8;   // MFMA A/B frag (4 VGPRs)
typedef __attribute__((ext_vector_type(4))) float  f32x4;    // MFMA C/D frag

// s_waitcnt simm16 (gfx9/CDNA): [3:0] vmcnt lo, [6:4] expcnt, [11:8] lgkmcnt, [15:14] vmcnt hi
#define WAITCNT_VM(n)   ((n & 0xF) | 0x70 | 0xF00 | (((n) >> 4) << 14))  // wait vmcnt<=n only
#define WAITCNT_LGKM(n) (0xF | 0x70 | ((n) << 8) | (3 << 14))            // wait lgkmcnt<=n only

__device__ __forceinline__ unsigned short f32_to_bf16(float f) {
    union { float f; unsigned int u; } cv;
    cv.f = f;
    unsigned int u = cv.u;
    return (unsigned short)((u + 0x7fffu + ((u >> 16) & 1u)) >> 16);  // RNE
}

__device__ __forceinline__ float bf16_to_f32(unsigned short h) {
    union { unsigned int u; float f; } cv;
    cv.u = ((unsigned int)h) << 16;
    return cv.f;
}

// async global->LDS, 16 bytes per lane. LDS dest is wave-uniform base + lane*16.
__device__ __forceinline__ void async_copy16(const unsigned short* g, unsigned short* lds) {
    __builtin_amdgcn_global_load_lds(
        (const __attribute__((address_space(1))) unsigned int*)g,
        (__attribute__((address_space(3))) unsigned int*)lds,
        16, 0, 0);
}

// ---------- fused fp32 -> bf16 cast for all five inputs + lsum zeroing ----------
__global__ __launch_bounds__(256) void cast_all(
    const float* __restrict__ x,  const float* __restrict__ y,
    const float* __restrict__ wq, const float* __restrict__ wk, const float* __restrict__ wv,
    unsigned short* __restrict__ xb,  unsigned short* __restrict__ yb,
    unsigned short* __restrict__ wqb, unsigned short* __restrict__ wkb,
    unsigned short* __restrict__ wvb, float* __restrict__ lsum)
{
    int b = blockIdx.x;
    if (b >= 11264) {   // last block: zero lsum[4096]
        float4 z = {0.f, 0.f, 0.f, 0.f};
#pragma unroll
        for (int t = 0; t < 4; ++t)
            ((float4*)lsum)[threadIdx.x * 4 + t] = z;
        return;
    }
    const float* s; unsigned short* d; int base;
    if      (b < 4096)  { s = x;  d = xb;  base = b; }
    else if (b < 8192)  { s = y;  d = yb;  base = b - 4096; }
    else if (b < 9216)  { s = wq; d = wqb; base = b - 8192; }
    else if (b < 10240) { s = wk; d = wkb; base = b - 9216; }
    else                { s = wv; d = wvb; base = b - 10240; }
    int i = base * 256 + threadIdx.x;
    float4 v = ((const float4*)s)[i];
    ushort4 o;
    o.x = f32_to_bf16(v.x);
    o.y = f32_to_bf16(v.y);
    o.z = f32_to_bf16(v.z);
    o.w = f32_to_bf16(v.w);
    ((ushort4*)d)[i] = o;
}

// ---------- 1-deep prefetch GEMM core, BK=32 (proven; used by proj only) ----------
__device__ __forceinline__ void gemm_core_pf(
    const unsigned short* __restrict__ A, const unsigned short* __restrict__ B,
    int K, int rowBase, int colBase, int kBeg, int kEnd,
    unsigned short* ldsA, unsigned short* ldsB, f32x4 acc[4][4])
{
    const int tid  = threadIdx.x;
    const int lane = tid & 63;
    const int wave = tid >> 6;
    const int quad = lane >> 4;
    const int r    = lane & 15;
    const int wm   = wave >> 1;
    const int wn   = wave & 1;

    const int c1 = tid + 256;
    const long aOff0 = (long)(rowBase + (tid >> 2)) * K + (tid & 3) * 8;
    const long aOff1 = (long)(rowBase + (c1  >> 2)) * K + (c1  & 3) * 8;
    const long bOff0 = (long)(colBase + (tid >> 2)) * K + (tid & 3) * 8;
    const long bOff1 = (long)(colBase + (c1  >> 2)) * K + (c1  & 3) * 8;
    unsigned short* ldsA0 = ldsA + tid * 8;
    unsigned short* ldsA1 = ldsA + c1 * 8;
    unsigned short* ldsB0 = ldsB + tid * 8;
    unsigned short* ldsB1 = ldsB + c1 * 8;

    const int aReadOff = (wm * 64 + r) * 32 + quad * 8;
    const int bReadOff = (wn * 64 + r) * 32 + quad * 8;

    const int nSteps = (kEnd - kBeg) >> 5;

    async_copy16(A + aOff0 + kBeg, ldsA0);
    async_copy16(A + aOff1 + kBeg, ldsA1);
    async_copy16(B + bOff0 + kBeg, ldsB0);
    async_copy16(B + bOff1 + kBeg, ldsB1);

    for (int s = 0; s < nSteps; ++s) {
        const int cur = (s & 1) << 12;          // 0 or 4096 elems
        const int nxt = cur ^ 4096;
        __builtin_amdgcn_s_waitcnt(0);          // tile s arrived
        __syncthreads();                        // visible to all; buf[nxt] free
        if (s + 1 < nSteps) {
            const int kn = kBeg + ((s + 1) << 5);
            async_copy16(A + aOff0 + kn, ldsA0 + nxt);
            async_copy16(A + aOff1 + kn, ldsA1 + nxt);
            async_copy16(B + bOff0 + kn, ldsB0 + nxt);
            async_copy16(B + bOff1 + kn, ldsB1 + nxt);
        }
        bf16x8 af[4], bfr[4];
#pragma unroll
        for (int i = 0; i < 4; ++i)
            af[i] = *(const bf16x8*)(ldsA + cur + aReadOff + i * 16 * 32);
#pragma unroll
        for (int j = 0; j < 4; ++j)
            bfr[j] = *(const bf16x8*)(ldsB + cur + bReadOff + j * 16 * 32);
#pragma unroll
        for (int i = 0; i < 4; ++i)
#pragma unroll
            for (int j = 0; j < 4; ++j)
                acc[i][j] = __builtin_amdgcn_mfma_f32_16x16x32_bf16(af[i], bfr[j], acc[i][j], 0, 0, 0);
    }
}

// ---------- batched projections: 768 blocks (3 problems x 256), K=1024 ----------
__global__ __launch_bounds__(256, 2)
void proj_batched(const unsigned short* __restrict__ xb, const unsigned short* __restrict__ yb,
                  const unsigned short* __restrict__ wqb, const unsigned short* __restrict__ wkb,
                  const unsigned short* __restrict__ wvb,
                  unsigned short* __restrict__ q, unsigned short* __restrict__ k,
                  unsigned short* __restrict__ vt,
                  const float* __restrict__ bq, const float* __restrict__ bk,
                  const float* __restrict__ bv)
{
    __shared__ __align__(16) unsigned short ldsA[2 * 128 * 32];
    __shared__ __align__(16) unsigned short ldsB[2 * 128 * 32];

    const int b = blockIdx.x;
    const int z = b >> 8;
    const int rb = b & 255;

    const unsigned short *A, *B;
    unsigned short* C;
    const float* bias;
    int N, rowBase, colBase;
    bool biasPerRow;
    if (z == 0) {
        A = xb; B = wqb; C = q; bias = bq; N = 1024; biasPerRow = false;
        colBase = (rb >> 5) * 128; rowBase = (rb & 31) * 128;
    } else if (z == 1) {
        A = yb; B = wkb; C = k; bias = bk; N = 1024; biasPerRow = false;
        colBase = (rb >> 5) * 128; rowBase = (rb & 31) * 128;
    } else {
        A = wvb; B = yb; C = vt; bias = bv; N = 4096; biasPerRow = true;
        colBase = (rb >> 3) * 128; rowBase = (rb & 7) * 128;
    }

    f32x4 acc[4][4];
#pragma unroll
    for (int i = 0; i < 4; ++i)
#pragma unroll
        for (int j = 0; j < 4; ++j)
            acc[i][j] = (f32x4){0.f, 0.f, 0.f, 0.f};

    gemm_core_pf(A, B, 1024, rowBase, colBase, 0, 1024, ldsA, ldsB, acc);

    const int lane = threadIdx.x & 63;
    const int wave = threadIdx.x >> 6;
    const int quad = lane >> 4;
    const int r    = lane & 15;
    const int orow0 = rowBase + (wave >> 1) * 64 + quad * 4;
    const int ocol0 = colBase + (wave & 1) * 64 + r;

#pragma unroll
    for (int i = 0; i < 4; ++i)
#pragma unroll
        for (int e = 0; e < 4; ++e) {
            const int row = orow0 + i * 16 + e;
            const float brow = biasPerRow ? bias[row] : 0.f;
#pragma unroll
            for (int j = 0; j < 4; ++j) {
                const int col = ocol0 + j * 16;
                const float bb = biasPerRow ? brow : bias[col];
                C[(long)row * N + col] = f32_to_bf16(acc[i][j][e] + bb);
            }
        }
}

// ========== 256x256 / BK=64 / 8-wave core: one-phase-lookahead + counted lgkm ==========
// Best-measured core of the session (scores 46.9 us @ 27% MfmaUtil, R3). Each phase
// issues only the NEXT phase's frag reads (4 or 8 b128) and waits with a COUNTED
// lgkmcnt that retires only the PREVIOUS phase's reads; stages at phase end after the
// barrier; counted vmcnt at the tile boundary only.
__device__ __forceinline__ void gemm256_core(
    const unsigned short* __restrict__ A, const unsigned short* __restrict__ B,
    int K, int rowBase, int colBase, int kBeg, int nTiles,
    unsigned short* lds, f32x4 acc[8][4])
{
    const int tid  = threadIdx.x;
    const int lane = tid & 63;
    const int wid  = tid >> 6;
    const int quad = lane >> 4;
    const int r    = lane & 15;
    const int wm   = wid >> 2;
    const int wn   = wid & 3;

    const int row0 = tid >> 3;
    const int chs8 = (((tid & 7) ^ (row0 & 7)) << 3);
    const unsigned short* As = A + (long)(rowBase + row0) * K + chs8 + kBeg;
    const unsigned short* Bs = B + (long)(colBase + row0) * K + chs8 + kBeg;
    const long rstep = (long)K * 64;
    const long hstep = (long)K * 128;
    unsigned short* ldsLane = lds + tid * 8;

    const int aRd = (wm << 13) + (r << 6);
    const int bRd = 16384 + (wn << 12) + (r << 6);
    const int sw0 = ((quad ^ (r & 7)) << 3);
    const int sw1 = (((quad + 4) ^ (r & 7)) << 3);

    auto STG = [&](const unsigned short* src, int ldsOff) {
        async_copy16(src,         ldsLane + ldsOff);
        async_copy16(src + rstep, ldsLane + ldsOff + 4096);
    };

    // prologue: T0 (A+B) -> buf0 (8 loads); B(T1) -> buf1 (4 loads)
    STG(As,         0);
    STG(As + hstep, 8192);
    STG(Bs,         16384);
    STG(Bs + hstep, 24576);
    if (nTiles > 1) {
        STG(Bs + 64,         32768 + 16384);
        STG(Bs + hstep + 64, 32768 + 24576);
    }
    __builtin_amdgcn_s_waitcnt(WAITCNT_VM(4));
    __builtin_amdgcn_s_barrier();
    __builtin_amdgcn_sched_barrier(0);

    bf16x8 aE[4], aO[4], bX[4], bY[4];
#pragma unroll
    for (int i = 0; i < 4; ++i)
        aE[i] = *(const bf16x8*)(lds + aRd + i * 1024 + sw0);
#pragma unroll
    for (int j = 0; j < 4; ++j)
        bX[j] = *(const bf16x8*)(lds + bRd + j * 1024 + sw0);

    for (int T = 0; T < nTiles; ++T) {
        const int cur = (T & 1) << 15;
        const int nxt = cur ^ 32768;

        // P0: read aO=a0h1; MFMA aE x bX -> acc[0..3]; stage A(T+1)h0
#pragma unroll
        for (int i = 0; i < 4; ++i)
            aO[i] = *(const bf16x8*)(lds + cur + aRd + (4 + i) * 1024 + sw0);
        __builtin_amdgcn_s_waitcnt(WAITCNT_LGKM(4));
        __builtin_amdgcn_sched_barrier(0);
        __builtin_amdgcn_s_setprio(1);
#pragma unroll
        for (int i = 0; i < 4; ++i)
#pragma unroll
            for (int j = 0; j < 4; ++j)
                acc[i][j] = __builtin_amdgcn_mfma_f32_16x16x32_bf16(aE[i], bX[j], acc[i][j], 0, 0, 0);
        __builtin_amdgcn_s_setprio(0);
        __builtin_amdgcn_sched_barrier(0);
        __builtin_amdgcn_s_barrier();
        if (T + 1 < nTiles) STG(As + (T + 1) * 64, nxt);

        // P1: read aE=a1h0, bY=b1; MFMA aO x bX -> acc[4..7]; stage A(T+1)h1
#pragma unroll
        for (int i = 0; i < 4; ++i)
            aE[i] = *(const bf16x8*)(lds + cur + aRd + i * 1024 + sw1);
#pragma unroll
        for (int j = 0; j < 4; ++j)
            bY[j] = *(const bf16x8*)(lds + cur + bRd + j * 1024 + sw1);
        __builtin_amdgcn_s_waitcnt(WAITCNT_LGKM(8));
        __builtin_amdgcn_sched_barrier(0);
        __builtin_amdgcn_s_setprio(1);
#pragma unroll
        for (int i = 0; i < 4; ++i)
#pragma unroll
            for (int j = 0; j < 4; ++j)
                acc[4 + i][j] = __builtin_amdgcn_mfma_f32_16x16x32_bf16(aO[i], bX[j], acc[4 + i][j], 0, 0, 0);
        __builtin_amdgcn_s_setprio(0);
        __builtin_amdgcn_sched_barrier(0);
        __builtin_amdgcn_s_barrier();
        if (T + 1 < nTiles) STG(As + hstep + (T + 1) * 64, nxt + 8192);

        // P2: read aO=a1h1; MFMA aE x bY -> acc[0..3]; stage B(T+2)h0
#pragma unroll
        for (int i = 0; i < 4; ++i)
            aO[i] = *(const bf16x8*)(lds + cur + aRd + (4 + i) * 1024 + sw1);
        __builtin_amdgcn_s_waitcnt(WAITCNT_LGKM(4));
        __builtin_amdgcn_sched_barrier(0);
        __builtin_amdgcn_s_setprio(1);
#pragma unroll
        for (int i = 0; i < 4; ++i)
#pragma unroll
            for (int j = 0; j < 4; ++j)
                acc[i][j] = __builtin_amdgcn_mfma_f32_16x16x32_bf16(aE[i], bY[j], acc[i][j], 0, 0, 0);
        __builtin_amdgcn_s_setprio(0);
        __builtin_amdgcn_sched_barrier(0);
        __builtin_amdgcn_s_barrier();
        if (T + 2 < nTiles) STG(Bs + (T + 2) * 64, cur + 16384);

        // P3: boundary; read aE,bX(T+1) from nxt; MFMA aO x bY; stage B(T+2)h1
        if (T + 1 < nTiles) {
            if (T + 2 < nTiles) __builtin_amdgcn_s_waitcnt(WAITCNT_VM(2));
            else                __builtin_amdgcn_s_waitcnt(WAITCNT_VM(0));
            __builtin_amdgcn_s_barrier();
            __builtin_amdgcn_sched_barrier(0);
#pragma unroll
            for (int i = 0; i < 4; ++i)
                aE[i] = *(const bf16x8*)(lds + nxt + aRd + i * 1024 + sw0);
#pragma unroll
            for (int j = 0; j < 4; ++j)
                bX[j] = *(const bf16x8*)(lds + nxt + bRd + j * 1024 + sw0);
            __builtin_amdgcn_s_waitcnt(WAITCNT_LGKM(8));
        } else {
            __builtin_amdgcn_s_waitcnt(WAITCNT_LGKM(0));
        }
        __builtin_amdgcn_sched_barrier(0);
        __builtin_amdgcn_s_setprio(1);
#pragma unroll
        for (int i = 0; i < 4; ++i)
#pragma unroll
            for (int j = 0; j < 4; ++j)
                acc[4 + i][j] = __builtin_amdgcn_mfma_f32_16x16x32_bf16(aO[i], bY[j], acc[4 + i][j], 0, 0, 0);
        __builtin_amdgcn_s_setprio(0);
        __builtin_amdgcn_sched_barrier(0);
        if (T + 2 < nTiles) STG(Bs + hstep + (T + 2) * 64, cur + 24576);
    }
}

// ---------- scores (256^2): P = exp2(scale2 * (q @ k^T)) bf16, lsum[row] += rowsum ----------
__global__ __launch_bounds__(512, 2)
void scores_gemm256(const unsigned short* __restrict__ q, const unsigned short* __restrict__ k,
                    unsigned short* __restrict__ P, float* __restrict__ lsum, float scale2)
{
    __shared__ __align__(16) unsigned short lds[2 * 32768];   // 128 KB

    const int bid = blockIdx.x;                    // 256 blocks
    const int swz = (bid & 7) * 32 + (bid >> 3);   // XCD-contiguous (256%8==0, bijective)
    const int mt = swz >> 4, nt = swz & 15;
    const int rowBase = mt * 256;
    const int colBase = nt * 256;

    f32x4 acc[8][4];
#pragma unroll
    for (int i = 0; i < 8; ++i)
#pragma unroll
        for (int j = 0; j < 4; ++j)
            acc[i][j] = (f32x4){0.f, 0.f, 0.f, 0.f};

    gemm256_core(q, k, 1024, rowBase, colBase, 0, 16, lds, acc);

    const int lane = threadIdx.x & 63;
    const int wid  = threadIdx.x >> 6;
    const int quad = lane >> 4;
    const int r    = lane & 15;
    const int orow0 = rowBase + (wid >> 2) * 128 + quad * 4;
    const int ocol0 = colBase + (wid & 3) * 64 + r;

#pragma unroll
    for (int mi = 0; mi < 8; ++mi)
#pragma unroll
        for (int e = 0; e < 4; ++e) {
            const int row = orow0 + mi * 16 + e;
            float rs = 0.f;
#pragma unroll
            for (int nj = 0; nj < 4; ++nj) {
                const float p = exp2f(acc[mi][nj][e] * scale2);
                rs += p;
                P[(long)row * 4096 + ocol0 + nj * 16] = f32_to_bf16(p);
            }
#pragma unroll
            for (int m = 1; m < 16; m <<= 1) rs += __shfl_xor(rs, m, 64);
            if (r == 0) atomicAdd(&lsum[row], rs);
        }
}

// ---------- output GEMM (256^2), split-K x4 ----------
// grid 256 = 16 mt x 4 nt x 4 z  -> exactly 1 block/CU, full machine.
template <int ATOMIC>
__global__ __launch_bounds__(512, 2)
void out_gemm256(const unsigned short* __restrict__ P, const unsigned short* __restrict__ vt,
                 void* __restrict__ Out)
{
    __shared__ __align__(16) unsigned short lds[2 * 32768];   // 128 KB

    const int bid = blockIdx.x;
    const int swz = (bid & 7) * 32 + (bid >> 3);
    const int z  = swz & 3;
    const int nt = (swz >> 2) & 3;
    const int mt = swz >> 4;
    const int rowBase = mt * 256;
    const int colBase = nt * 256;
    const int kBeg = z * 1024;

    f32x4 acc[8][4];
#pragma unroll
    for (int i = 0; i < 8; ++i)
#pragma unroll
        for (int j = 0; j < 4; ++j)
            acc[i][j] = (f32x4){0.f, 0.f, 0.f, 0.f};

    gemm256_core(P, vt, 4096, rowBase, colBase, kBeg, 16, lds, acc);

    const int lane = threadIdx.x & 63;
    const int wid  = threadIdx.x >> 6;
    const int quad = lane >> 4;
    const int r    = lane & 15;
    const int orow0 = rowBase + (wid >> 2) * 128 + quad * 4;
    const int ocol0 = colBase + (wid & 3) * 64 + r;

#pragma unroll
    for (int mi = 0; mi < 8; ++mi)
#pragma unroll
        for (int e = 0; e < 4; ++e) {
            const int row = orow0 + mi * 16 + e;
#pragma unroll
            for (int nj = 0; nj < 4; ++nj) {
                const int col = ocol0 + nj * 16;
                if (ATOMIC) {
                    atomicAdd(&((float*)Out)[(long)row * 1024 + col], acc[mi][nj][e]);
                } else {
                    unsigned short* parts = (unsigned short*)Out + (size_t)z * (4096 * 1024);
                    parts[(long)row * 1024 + col] = f32_to_bf16(acc[mi][nj][e]);
                }
            }
        }
}

// ---------- reduce 4 bf16 partials + normalize: O = (P0+P1+P2+P3) / lsum[row] ----------
__global__ __launch_bounds__(256) void reduce_norm4(const unsigned short* __restrict__ parts,
                                                    const float* __restrict__ lsum,
                                                    float* __restrict__ O) {
    const int i = blockIdx.x * 256 + threadIdx.x;   // ushort4 group index; 256 per row
    const float inv = 1.0f / lsum[i >> 8];
    const size_t stride = (size_t)(4096 * 1024) / 4;   // ushort4 units
    ushort4 a = ((const ushort4*)parts)[i];
    ushort4 b = ((const ushort4*)parts)[i + stride];
    ushort4 c = ((const ushort4*)parts)[i + 2 * stride];
    ushort4 d = ((const ushort4*)parts)[i + 3 * stride];
    float4 o;
    o.x = (bf16_to_f32(a.x) + bf16_to_f32(b.x) + bf16_to_f32(c.x) + bf16_to_f32(d.x)) * inv;
    o.y = (bf16_to_f32(a.y) + bf16_to_f32(b.y) + bf16_to_f32(c.y) + bf16_to_f32(d.y)) * inv;
    o.z = (bf16_to_f32(a.z) + bf16_to_f32(b.z) + bf16_to_f32(c.z) + bf16_to_f32(d.z)) * inv;
    o.w = (bf16_to_f32(a.w) + bf16_to_f32(b.w) + bf16_to_f32(c.w) + bf16_to_f32(d.w)) * inv;
    ((float4*)O)[i] = o;
}

// ---------- normalize in place (atomic fallback path) ----------
__global__ __launch_bounds__(256) void norm_rows(float* __restrict__ O, const float* __restrict__ lsum) {
    int i = blockIdx.x * 256 + threadIdx.x;
    const float inv = 1.0f / lsum[i >> 8];
    float4 v = ((const float4*)O)[i];
    v.x *= inv; v.y *= inv; v.z *= inv; v.w *= inv;
    ((float4*)O)[i] = v;
}

extern "C" void kernel_launch(void* const* d_in, const int* in_sizes, int n_in,
                              void* d_out, int out_size, void* d_ws, size_t ws_size,
                              hipStream_t stream) {
    const float* x  = (const float*)d_in[0];
    const float* y  = (const float*)d_in[1];
    const float* Wq = (const float*)d_in[2];
    const float* bq = (const float*)d_in[3];
    const float* Wk = (const float*)d_in[4];
    const float* bk = (const float*)d_in[5];
    const float* Wv = (const float*)d_in[6];
    const float* bv = (const float*)d_in[7];

    constexpr int Nx = 4096, Ny = 4096, H = 1024, Dv = 1024, Kin = 1024;

    char* ws = (char*)d_ws;
    size_t off = 0;
    auto carve = [&](size_t bytes) {
        char* p = ws + off;
        off += (bytes + 255) & ~(size_t)255;
        return p;
    };

    unsigned short* q_bf  = (unsigned short*)carve((size_t)Nx * H * 2);   // 8 MB
    unsigned short* k_bf  = (unsigned short*)carve((size_t)Ny * H * 2);   // 8 MB
    unsigned short* vt_bf = (unsigned short*)carve((size_t)Dv * Ny * 2);  // 8 MB
    float*          lsum  = (float*)carve((size_t)Nx * sizeof(float));    // 16 KB

    // overlay: phase 1 = bf16 casts (22 MB), phase 2 = P (32 MB)
    char* overlay = ws + off;
    unsigned short* x_bf  = (unsigned short*)overlay;
    unsigned short* y_bf  = x_bf  + (size_t)Nx * Kin;
    unsigned short* Wq_bf = y_bf  + (size_t)Ny * Kin;
    unsigned short* Wk_bf = Wq_bf + (size_t)H  * Kin;
    unsigned short* Wv_bf = Wk_bf + (size_t)H  * Kin;
    unsigned short* P_bf  = (unsigned short*)overlay;  // [Nx, Ny] bf16, phase 2

    // bf16 partials after the P region: 4 x 8 MB (split-K x4)
    const size_t overlay_bytes = (size_t)Nx * Ny * 2;                 // 32 MB
    const size_t partsBytes = (size_t)Nx * Dv * 2;                    // 8 MB each
    unsigned short* parts = (unsigned short*)(overlay + overlay_bytes);
    const size_t need_parts = (size_t)((overlay + overlay_bytes + 4 * partsBytes) - ws);
    const bool useParts = ws_size >= need_parts;

    if (!useParts)
        (void)hipMemsetAsync(d_out, 0, (size_t)Nx * Dv * sizeof(float), stream);

    // phase 0: all casts + lsum zeroing, one launch
    cast_all<<<11265, 256, 0, stream>>>(x, y, Wq, Wk, Wv, x_bf, y_bf, Wq_bf, Wk_bf, Wv_bf, lsum);

    // phase 1: all three projections, one launch (768 blocks)
    proj_batched<<<768, 256, 0, stream>>>(x_bf, y_bf, Wq_bf, Wk_bf, Wv_bf,
                                          q_bf, k_bf, vt_bf, bq, bk, bv);

    // phase 2a: P = exp(q k^T / 32), lsum row sums (256 blocks x 512, lookahead core)
    const float scale2 = 1.4426950408889634f / 32.0f;  // log2(e)/sqrt(H)
    scores_gemm256<<<256, 512, 0, stream>>>(q_bf, k_bf, P_bf, lsum, scale2);

    // phase 2b: split-K x4, lookahead core, bf16 partials (256 blocks x 512 = 1/CU)
    if (useParts) {
        out_gemm256<0><<<256, 512, 0, stream>>>(P_bf, vt_bf, parts);
        reduce_norm4<<<(Nx * Dv / 4) / 256, 256, 0, stream>>>(parts, lsum, (float*)d_out);
    } else {
        out_gemm256<1><<<256, 512, 0, stream>>>(P_bf, vt_bf, d_out);
        norm_rows<<<Nx * Dv / 4 / 256, 256, 0, stream>>>((float*)d_out, lsum);
    }
}